// Round 4
// baseline (457.774 us; speedup 1.0000x reference)
//
#include <hip/hip_runtime.h>
#include <math.h>

// Geometry fixed by reference setup_inputs
#define GG 52
#define AA 3
#define BB 16
#define DD 85
#define NCELL (GG*GG*AA)           // 8112 cells per batch
#define EBAT (NCELL*DD)            // 689520 floats per batch
#define TOTV ((BB*EBAT)/4)         // 2,758,080 float4s (flat over all batches)
#define NA_BLK 1536                // pass-A blocks (uniform BCE stream)
#define NWAVES (NA_BLK*4)          // 6144 pass-A waves
#define CHUNK 452                  // ceil(TOTV/NWAVES) rounded up to mult of 4
#define NB_BLK_PB 32               // pass-B blocks per batch (8192 thr >= 8112 cells)
#define NB_BLK (NB_BLK_PB*BB)      // 512
#define NT 256
#define LN2 0.69314718055994530942f

// ws layout (floats): [0 .. NA_BLK*2)          pass-A partials {sumH, sumLog2}
//                     [NA_BLK*2 .. +NB_BLK*4)  pass-B partials {s1, s2, bce5, bceObj}

__device__ __forceinline__ float fast_sig(float x) {
  float u = __expf(-fabsf(x));
  float r = __builtin_amdgcn_rcpf(1.0f + u);
  return x >= 0.0f ? r : u * r;
}
// bce(sigmoid(x), t) = max(x,0) - x*t + ln(1+exp(-|x|))
__device__ __forceinline__ float fast_bce(float x, float t) {
  float u = __expf(-fabsf(x));
  return fmaxf(x, 0.0f) - x * t + LN2 * __log2f(1.0f + u);
}

// Accumulate BCE pieces for 4 (x,t) pairs: aA += -x*t, aB += max(x,0),
// pr0/pr1 *= (1+exp(-|x|))  (log2 taken once per 16 elements by caller)
__device__ __forceinline__ void elem4(float4 p, float4 t,
                                      float& aA, float& aB, float& pr0, float& pr1) {
  #pragma unroll
  for (int k = 0; k < 4; ++k) {
    float x = (&p.x)[k], tt = (&t.x)[k];
    float u = __expf(-fabsf(x));               // v_mul(-|x|*log2e) + v_exp
    aA = fmaf(-x, tt, aA);
    aB += fmaxf(x, 0.0f);
    if (k & 1) pr1 = fmaf(pr1, u, pr1);        // pr *= (1+u), 2 indep chains
    else       pr0 = fmaf(pr0, u, pr0);
  }
}

__global__ __launch_bounds__(NT, 4) void yolo_pass(
    const float* __restrict__ yp, const float* __restrict__ yt,
    const float* __restrict__ anch, float* __restrict__ ws)
{
  const int bx = blockIdx.x;
  const int lane = threadIdx.x & 63, wid = threadIdx.x >> 6;

  if (bx < NA_BLK) {
    // ---------- pass A: uniform BCE over every element of both-batch stream ----
    const float4* __restrict__ vp = (const float4*)yp;
    const float4* __restrict__ vt = (const float4*)yt;
    const int gw = bx * 4 + wid;               // global wave id
    const int base = gw * CHUNK;               // this wave's float4 range start
    float aA = 0.f, aB = 0.f, sl = 0.f;

    if (base + CHUNK <= TOTV) {                // fast path: no bounds checks
      int v = base + lane;
      for (int i = 0; i < CHUNK / 4; ++i) {
        float4 p0 = vp[v],       t0 = vt[v];
        float4 p1 = vp[v + 64],  t1 = vt[v + 64];
        float4 p2 = vp[v + 128], t2 = vt[v + 128];
        float4 p3 = vp[v + 192], t3 = vt[v + 192];
        float pr0 = 1.f, pr1 = 1.f;
        elem4(p0, t0, aA, aB, pr0, pr1);
        elem4(p1, t1, aA, aB, pr0, pr1);
        elem4(p2, t2, aA, aB, pr0, pr1);
        elem4(p3, t3, aA, aB, pr0, pr1);
        sl += __log2f(pr0 * pr1);              // 1 log2 per 16 elements
        v += 256;
      }
    } else {                                   // last ~42 waves: checked
      for (int i = 0; i < CHUNK; ++i) {
        int v = base + lane + i * 64;
        if (v < TOTV) {
          float4 p = vp[v], t = vt[v];
          float pr0 = 1.f, pr1 = 1.f;
          elem4(p, t, aA, aB, pr0, pr1);
          sl += __log2f(pr0 * pr1);
        }
      }
    }
    float sh = aA + aB;
    for (int off = 32; off > 0; off >>= 1) {
      sh += __shfl_down(sh, off); sl += __shfl_down(sl, off);
    }
    __shared__ float lds[NT / 64][2];
    if (lane == 0) { lds[wid][0] = sh; lds[wid][1] = sl; }
    __syncthreads();
    if (threadIdx.x == 0) {
      float r0 = 0, r1 = 0;
      #pragma unroll
      for (int w = 0; w < NT / 64; ++w) { r0 += lds[w][0]; r1 += lds[w][1]; }
      ws[bx * 2 + 0] = r0;
      ws[bx * 2 + 1] = r1;
    }
  } else {
    // ---------- pass B: one thread per cell, channels 0..4 only ----------------
    const int j = bx - NA_BLK;                 // 0..511
    const int b = j >> 5;                      // batch
    const int cell = (j & 31) * NT + threadIdx.x;
    float s1 = 0.f, s2 = 0.f, b5 = 0.f, bo = 0.f;
    if (cell < NCELL) {
      const float* pp = yp + ((size_t)b * NCELL + cell) * DD;
      const float* tt = yt + ((size_t)b * NCELL + cell) * DD;
      float x0 = pp[0], x1 = pp[1], x2 = pp[2], x3 = pp[3], x4 = pp[4];
      float t0 = tt[0], t1 = tt[1], t2 = tt[2], t3 = tt[3], t4 = tt[4];
      int gi = cell / (GG * AA);               // meshgrid 'ij' dim-1
      int gj = (cell / AA) % GG;               // dim-2
      int a  = cell % AA;
      float aw = anch[a * 2 + 0], ah = anch[a * 2 + 1];
      float d0 = (t0 * (float)GG - (float)gi) - fast_sig(x0);
      float d1 = (t1 * (float)GG - (float)gj) - fast_sig(x1);
      float d2 = ((t2 > 0.f) ? (__logf(t2) - __logf(aw)) : 0.f) - fast_sig(x2);
      float d3 = ((t3 > 0.f) ? (__logf(t3) - __logf(ah)) : 0.f) - fast_sig(x3);
      s1 = (d0 * d0 + d1 * d1 + d2 * d2 + d3 * d3) * t4;
      s2 = t4;
      float b4 = fast_bce(x4, t4);
      b5 = fast_bce(x0, t0) + fast_bce(x1, t1) + fast_bce(x2, t2) + fast_bce(x3, t3) + b4;
      bo = b4;
    }
    float v0 = s1, v1 = s2, v2 = b5, v3 = bo;
    for (int off = 32; off > 0; off >>= 1) {
      v0 += __shfl_down(v0, off); v1 += __shfl_down(v1, off);
      v2 += __shfl_down(v2, off); v3 += __shfl_down(v3, off);
    }
    __shared__ float lds4[NT / 64][4];
    if (lane == 0) { lds4[wid][0] = v0; lds4[wid][1] = v1; lds4[wid][2] = v2; lds4[wid][3] = v3; }
    __syncthreads();
    if (threadIdx.x == 0) {
      float r0 = 0, r1 = 0, r2 = 0, r3 = 0;
      #pragma unroll
      for (int w = 0; w < NT / 64; ++w) {
        r0 += lds4[w][0]; r1 += lds4[w][1]; r2 += lds4[w][2]; r3 += lds4[w][3];
      }
      float* dst = ws + NA_BLK * 2 + j * 4;
      dst[0] = r0; dst[1] = r1; dst[2] = r2; dst[3] = r3;
    }
  }
}

__global__ __launch_bounds__(256) void yolo_fin(
    const float* __restrict__ ws, float* __restrict__ out)
{
  const int tid = threadIdx.x;
  float sh = 0.f, sl = 0.f, b5 = 0.f, bo = 0.f;
  for (int i = tid; i < NA_BLK; i += 256) { sh += ws[i * 2]; sl += ws[i * 2 + 1]; }
  const float* pb = ws + NA_BLK * 2;
  for (int i = tid; i < NB_BLK; i += 256) { b5 += pb[i * 4 + 2]; bo += pb[i * 4 + 3]; }
  for (int off = 32; off > 0; off >>= 1) {
    sh += __shfl_down(sh, off); sl += __shfl_down(sl, off);
    b5 += __shfl_down(b5, off); bo += __shfl_down(bo, off);
  }
  __shared__ float red[4][4];
  int lane = tid & 63, wid = tid >> 6;
  if (lane == 0) { red[wid][0] = sh; red[wid][1] = sl; red[wid][2] = b5; red[wid][3] = bo; }
  __syncthreads();
  __shared__ float coef;
  if (tid == 0) {
    float SH = 0, SL = 0, B5 = 0, BO = 0;
    #pragma unroll
    for (int w = 0; w < 4; ++w) {
      SH += red[w][0]; SL += red[w][1]; B5 += red[w][2]; BO += red[w][3];
    }
    float all = SH + LN2 * SL;          // BCE sum over all 85 channels
    float cls = all - B5;               // classes only (c >= 5)
    const float ncls = (float)BB * (float)NCELL * 80.0f;   // 10,383,360 (<2^24)
    const float nobj = (float)BB * (float)NCELL;           // 129,792
    coef = 0.5f * cls / ncls + BO / nobj;
  }
  __syncthreads();
  if (tid < BB) {
    const float* pb2 = ws + NA_BLK * 2;
    float s1 = 0.f, s2 = 0.f;
    for (int j = 0; j < NB_BLK_PB; ++j) {
      int idx = (tid * NB_BLK_PB + j) * 4;
      s1 += pb2[idx + 0]; s2 += pb2[idx + 1];
    }
    out[tid] = 2.0f * s1 + coef * s2;
  }
}

extern "C" void kernel_launch(void* const* d_in, const int* in_sizes, int n_in,
                              void* d_out, int out_size, void* d_ws, size_t ws_size,
                              hipStream_t stream) {
  const float* yp   = (const float*)d_in[0];   // y_pred (16,52,52,3,85)
  const float* yt   = (const float*)d_in[1];   // y_true (16,52,52,3,85)
  const float* anch = (const float*)d_in[2];   // (3,2)
  float* out = (float*)d_out;                  // (16,)
  float* ws  = (float*)d_ws;                   // (1536*2 + 512*4)*4 = 20 KB

  yolo_pass<<<NA_BLK + NB_BLK, NT, 0, stream>>>(yp, yt, anch, ws);
  yolo_fin<<<1, 256, 0, stream>>>(ws, out);
}

// Round 5
// 111.460 us; speedup vs baseline: 4.1071x; 4.1071x over previous
//
#include <hip/hip_runtime.h>
#include <math.h>

// Geometry fixed by reference setup_inputs
#define GG 52
#define AA 3
#define BB 16
#define DD 85
#define NCELL (GG*GG*AA)           // 8112 cells per batch
#define EBAT (NCELL*DD)            // 689520 floats per batch
#define TOTV ((BB*EBAT)/4)         // 2,758,080 float4s, flat over all batches
#define NA_BLK 2048                // pass-A blocks (uniform BCE stream)
#define NB_BLK_PB 32               // pass-B blocks per batch
#define NB_BLK (NB_BLK_PB*BB)      // 512
#define NBLK (NA_BLK+NB_BLK)       // 2560 total blocks
#define NT 256
#define STRIDE (NA_BLK*NT)         // 524288 pass-A threads
#define LN2 0.69314718055994530942f

// ws layout (floats):
//   [0]                     counter (unsigned; memset to 0 every launch)
//   [WS_A .. WS_A+NA_BLK*2) pass-A partials {sumH, sumLog2}
//   [WS_B .. WS_B+NB_BLK*4) pass-B partials {s1, s2, bce5, bceObj}
#define WS_A 8
#define WS_B (WS_A + NA_BLK*2)

__device__ __forceinline__ float fast_sig(float x) {
  float u = __expf(-fabsf(x));
  float r = __builtin_amdgcn_rcpf(1.0f + u);
  return x >= 0.0f ? r : u * r;
}
// bce(sigmoid(x), t) = max(x,0) - x*t + ln(1+exp(-|x|))
__device__ __forceinline__ float fast_bce(float x, float t) {
  float u = __expf(-fabsf(x));
  return fmaxf(x, 0.0f) - x * t + LN2 * __log2f(1.0f + u);
}
// BCE pieces for 4 (x,t): aA += -x*t, aB += max(x,0), pr0/pr1 *= (1+exp(-|x|))
__device__ __forceinline__ void elem4(float4 p, float4 t,
                                      float& aA, float& aB, float& pr0, float& pr1) {
  #pragma unroll
  for (int k = 0; k < 4; ++k) {
    float x = (&p.x)[k], tt = (&t.x)[k];
    float u = __expf(-fabsf(x));
    aA = fmaf(-x, tt, aA);
    aB += fmaxf(x, 0.0f);
    if (k & 1) pr1 = fmaf(pr1, u, pr1);   // pr *= (1+u), two indep chains
    else       pr0 = fmaf(pr0, u, pr0);
  }
}

__global__ __launch_bounds__(NT) void yolo_fused(
    const float* __restrict__ yp, const float* __restrict__ yt,
    const float* __restrict__ anch, float* __restrict__ ws,
    unsigned* __restrict__ ctr, float* __restrict__ out)
{
  const int bx = blockIdx.x;
  const int lane = threadIdx.x & 63, wid = threadIdx.x >> 6;
  __shared__ float lds[NT / 64][4];

  if (bx < NA_BLK) {
    // ---------- pass A: uniform BCE over all 85 channels, fully coalesced -----
    const float4* __restrict__ vp = (const float4*)yp;
    const float4* __restrict__ vt = (const float4*)yt;
    float aA = 0.f, aB = 0.f, sl = 0.f;
    int v = bx * NT + threadIdx.x;
    // covers [0, TOTV) exactly once: verified (TOTV = 5.2606*STRIDE)
    while (v + STRIDE < TOTV) {
      float4 pa = vp[v],          ta = vt[v];
      float4 pb = vp[v + STRIDE], tb = vt[v + STRIDE];
      float pr0 = 1.f, pr1 = 1.f;
      elem4(pa, ta, aA, aB, pr0, pr1);
      elem4(pb, tb, aA, aB, pr0, pr1);
      sl += __log2f(pr0 * pr1);           // 1 log2 per 8 elements, prod <= 256
      v += 2 * STRIDE;
    }
    if (v < TOTV) {
      float4 pa = vp[v], ta = vt[v];
      float pr0 = 1.f, pr1 = 1.f;
      elem4(pa, ta, aA, aB, pr0, pr1);
      sl += __log2f(pr0 * pr1);
    }
    float sh = aA + aB;
    for (int off = 32; off > 0; off >>= 1) {
      sh += __shfl_down(sh, off); sl += __shfl_down(sl, off);
    }
    if (lane == 0) { lds[wid][0] = sh; lds[wid][1] = sl; }
    __syncthreads();
    if (threadIdx.x == 0) {
      float r0 = 0, r1 = 0;
      #pragma unroll
      for (int w = 0; w < NT / 64; ++w) { r0 += lds[w][0]; r1 += lds[w][1]; }
      ws[WS_A + bx * 2 + 0] = r0;
      ws[WS_A + bx * 2 + 1] = r1;
    }
  } else {
    // ---------- pass B: one thread per cell, channels 0..4 only ---------------
    const int j = bx - NA_BLK;            // 0..511
    const int b = j >> 5;                 // batch
    const int cell = (j & 31) * NT + threadIdx.x;
    float s1 = 0.f, s2 = 0.f, b5 = 0.f, bo = 0.f;
    if (cell < NCELL) {
      const float* pp = yp + ((size_t)b * NCELL + cell) * DD;
      const float* tt = yt + ((size_t)b * NCELL + cell) * DD;
      float x0 = pp[0], x1 = pp[1], x2 = pp[2], x3 = pp[3], x4 = pp[4];
      float t0 = tt[0], t1 = tt[1], t2 = tt[2], t3 = tt[3], t4 = tt[4];
      int gi = cell / (GG * AA);          // meshgrid 'ij' dim-1
      int gj = (cell / AA) % GG;          // dim-2
      int a  = cell % AA;
      float aw = anch[a * 2 + 0], ah = anch[a * 2 + 1];
      float d0 = (t0 * (float)GG - (float)gi) - fast_sig(x0);
      float d1 = (t1 * (float)GG - (float)gj) - fast_sig(x1);
      float d2 = ((t2 > 0.f) ? (__logf(t2) - __logf(aw)) : 0.f) - fast_sig(x2);
      float d3 = ((t3 > 0.f) ? (__logf(t3) - __logf(ah)) : 0.f) - fast_sig(x3);
      s1 = (d0 * d0 + d1 * d1 + d2 * d2 + d3 * d3) * t4;
      s2 = t4;
      float b4 = fast_bce(x4, t4);
      b5 = fast_bce(x0, t0) + fast_bce(x1, t1) + fast_bce(x2, t2) + fast_bce(x3, t3) + b4;
      bo = b4;
    }
    float v0 = s1, v1 = s2, v2 = b5, v3 = bo;
    for (int off = 32; off > 0; off >>= 1) {
      v0 += __shfl_down(v0, off); v1 += __shfl_down(v1, off);
      v2 += __shfl_down(v2, off); v3 += __shfl_down(v3, off);
    }
    if (lane == 0) { lds[wid][0] = v0; lds[wid][1] = v1; lds[wid][2] = v2; lds[wid][3] = v3; }
    __syncthreads();
    if (threadIdx.x == 0) {
      float r0 = 0, r1 = 0, r2 = 0, r3 = 0;
      #pragma unroll
      for (int w = 0; w < NT / 64; ++w) {
        r0 += lds[w][0]; r1 += lds[w][1]; r2 += lds[w][2]; r3 += lds[w][3];
      }
      float* dst = ws + WS_B + j * 4;
      dst[0] = r0; dst[1] = r1; dst[2] = r2; dst[3] = r3;
    }
  }

  // ---------- last-block-done finalize --------------------------------------
  __shared__ int isLast;
  __syncthreads();                         // partials written (thread 0 store done)
  if (threadIdx.x == 0) {
    __threadfence();                       // release: make partials device-visible
    unsigned old = atomicAdd(ctr, 1u);
    isLast = (old == (unsigned)(NBLK - 1));
  }
  __syncthreads();
  if (!isLast) return;
  __threadfence();                         // acquire: all threads, before reading partials

  float sh = 0.f, sl = 0.f, b5 = 0.f, bo = 0.f;
  for (int i = threadIdx.x; i < NA_BLK; i += NT) {
    sh += ws[WS_A + i * 2]; sl += ws[WS_A + i * 2 + 1];
  }
  for (int i = threadIdx.x; i < NB_BLK; i += NT) {
    b5 += ws[WS_B + i * 4 + 2]; bo += ws[WS_B + i * 4 + 3];
  }
  for (int off = 32; off > 0; off >>= 1) {
    sh += __shfl_down(sh, off); sl += __shfl_down(sl, off);
    b5 += __shfl_down(b5, off); bo += __shfl_down(bo, off);
  }
  __syncthreads();                         // lds reuse
  if (lane == 0) { lds[wid][0] = sh; lds[wid][1] = sl; lds[wid][2] = b5; lds[wid][3] = bo; }
  __syncthreads();
  __shared__ float coef;
  if (threadIdx.x == 0) {
    float SH = 0, SL = 0, B5 = 0, BO = 0;
    #pragma unroll
    for (int w = 0; w < NT / 64; ++w) {
      SH += lds[w][0]; SL += lds[w][1]; B5 += lds[w][2]; BO += lds[w][3];
    }
    float all = SH + LN2 * SL;             // BCE sum, all 85 channels
    float cls = all - B5;                  // classes only (c >= 5)
    const float ncls = (float)BB * (float)NCELL * 80.0f;   // 10,383,360 (<2^24)
    const float nobj = (float)BB * (float)NCELL;           // 129,792
    coef = 0.5f * cls / ncls + BO / nobj;
  }
  __syncthreads();
  if (threadIdx.x < BB) {
    float s1 = 0.f, s2 = 0.f;
    for (int k = 0; k < NB_BLK_PB; ++k) {
      int idx = WS_B + (threadIdx.x * NB_BLK_PB + k) * 4;
      s1 += ws[idx + 0]; s2 += ws[idx + 1];
    }
    out[threadIdx.x] = 2.0f * s1 + coef * s2;
  }
}

extern "C" void kernel_launch(void* const* d_in, const int* in_sizes, int n_in,
                              void* d_out, int out_size, void* d_ws, size_t ws_size,
                              hipStream_t stream) {
  const float* yp   = (const float*)d_in[0];   // y_pred (16,52,52,3,85)
  const float* yt   = (const float*)d_in[1];   // y_true (16,52,52,3,85)
  const float* anch = (const float*)d_in[2];   // (3,2)
  float* out = (float*)d_out;                  // (16,)
  float* ws  = (float*)d_ws;                   // needs (8 + 2048*2 + 512*4)*4 B < 25 KB
  unsigned* ctr = (unsigned*)d_ws;             // counter at ws[0]

  hipMemsetAsync(ctr, 0, sizeof(unsigned), stream);   // graph-capturable memset node
  yolo_fused<<<NBLK, NT, 0, stream>>>(yp, yt, anch, ws, ctr, out);
}

// Round 6
// 29.595 us; speedup vs baseline: 15.4680x; 3.7662x over previous
//
#include <hip/hip_runtime.h>
#include <math.h>

// Geometry fixed by reference setup_inputs
#define GG 52
#define AA 3
#define BB 16
#define DD 85
#define NCELL (GG*GG*AA)           // 8112 cells per batch
#define EBAT (NCELL*DD)            // 689520 floats per batch
#define TOTV ((BB*EBAT)/4)         // 2,758,080 float4s, flat over all batches
#define NA_BLK 2048                // pass-A blocks (uniform BCE stream)
#define NB_BLK_PB 32               // pass-B blocks per batch
#define NB_BLK (NB_BLK_PB*BB)      // 512
#define NBLK (NA_BLK+NB_BLK)       // 2560 blocks in main dispatch
#define NT 256
#define STRIDE (NA_BLK*NT)         // 524288 pass-A threads
#define LN2 0.69314718055994530942f

// ws layout (floats): [0 .. NA_BLK*2)          pass-A partials {sumH, sumLog2}
//                     [WS_B .. WS_B+NB_BLK*4)  pass-B partials {s1, s2, bce5, bceObj}
#define WS_B (NA_BLK*2)

__device__ __forceinline__ float fast_sig(float x) {
  float u = __expf(-fabsf(x));
  float r = __builtin_amdgcn_rcpf(1.0f + u);
  return x >= 0.0f ? r : u * r;
}
// bce(sigmoid(x), t) = max(x,0) - x*t + ln(1+exp(-|x|))
__device__ __forceinline__ float fast_bce(float x, float t) {
  float u = __expf(-fabsf(x));
  return fmaxf(x, 0.0f) - x * t + LN2 * __log2f(1.0f + u);
}
// BCE pieces for 4 (x,t): aA += -x*t, aB += max(x,0), pr0/pr1 *= (1+exp(-|x|))
__device__ __forceinline__ void elem4(float4 p, float4 t,
                                      float& aA, float& aB, float& pr0, float& pr1) {
  #pragma unroll
  for (int k = 0; k < 4; ++k) {
    float x = (&p.x)[k], tt = (&t.x)[k];
    float u = __expf(-fabsf(x));
    aA = fmaf(-x, tt, aA);
    aB += fmaxf(x, 0.0f);
    if (k & 1) pr1 = fmaf(pr1, u, pr1);   // pr *= (1+u), two indep chains
    else       pr0 = fmaf(pr0, u, pr0);
  }
}

__global__ __launch_bounds__(NT) void yolo_pass(
    const float* __restrict__ yp, const float* __restrict__ yt,
    const float* __restrict__ anch, float* __restrict__ ws)
{
  const int bx = blockIdx.x;
  const int lane = threadIdx.x & 63, wid = threadIdx.x >> 6;
  __shared__ float lds[NT / 64][4];

  if (bx < NA_BLK) {
    // ---------- pass A: uniform BCE over all 85 channels, fully coalesced -----
    const float4* __restrict__ vp = (const float4*)yp;
    const float4* __restrict__ vt = (const float4*)yt;
    float aA = 0.f, aB = 0.f, sl = 0.f;
    int v = bx * NT + threadIdx.x;
    // covers [0, TOTV) exactly once (TOTV = 5*STRIDE + 136640; hand-verified)
    while (v + STRIDE < TOTV) {
      float4 pa = vp[v],          ta = vt[v];
      float4 pb = vp[v + STRIDE], tb = vt[v + STRIDE];
      float pr0 = 1.f, pr1 = 1.f;
      elem4(pa, ta, aA, aB, pr0, pr1);
      elem4(pb, tb, aA, aB, pr0, pr1);
      sl += __log2f(pr0 * pr1);           // 1 log2 per 8 elements, prod <= 256
      v += 2 * STRIDE;
    }
    if (v < TOTV) {
      float4 pa = vp[v], ta = vt[v];
      float pr0 = 1.f, pr1 = 1.f;
      elem4(pa, ta, aA, aB, pr0, pr1);
      sl += __log2f(pr0 * pr1);
    }
    float sh = aA + aB;
    for (int off = 32; off > 0; off >>= 1) {
      sh += __shfl_down(sh, off); sl += __shfl_down(sl, off);
    }
    if (lane == 0) { lds[wid][0] = sh; lds[wid][1] = sl; }
    __syncthreads();
    if (threadIdx.x == 0) {
      float r0 = 0, r1 = 0;
      #pragma unroll
      for (int w = 0; w < NT / 64; ++w) { r0 += lds[w][0]; r1 += lds[w][1]; }
      ws[bx * 2 + 0] = r0;
      ws[bx * 2 + 1] = r1;
    }
  } else {
    // ---------- pass B: one thread per cell, channels 0..4 only ---------------
    const int j = bx - NA_BLK;            // 0..511
    const int b = j >> 5;                 // batch
    const int cell = (j & 31) * NT + threadIdx.x;
    float s1 = 0.f, s2 = 0.f, b5 = 0.f, bo = 0.f;
    if (cell < NCELL) {
      const float* pp = yp + ((size_t)b * NCELL + cell) * DD;
      const float* tt = yt + ((size_t)b * NCELL + cell) * DD;
      float x0 = pp[0], x1 = pp[1], x2 = pp[2], x3 = pp[3], x4 = pp[4];
      float t0 = tt[0], t1 = tt[1], t2 = tt[2], t3 = tt[3], t4 = tt[4];
      int gi = cell / (GG * AA);          // meshgrid 'ij' dim-1
      int gj = (cell / AA) % GG;          // dim-2
      int a  = cell % AA;
      float aw = anch[a * 2 + 0], ah = anch[a * 2 + 1];
      float d0 = (t0 * (float)GG - (float)gi) - fast_sig(x0);
      float d1 = (t1 * (float)GG - (float)gj) - fast_sig(x1);
      float d2 = ((t2 > 0.f) ? (__logf(t2) - __logf(aw)) : 0.f) - fast_sig(x2);
      float d3 = ((t3 > 0.f) ? (__logf(t3) - __logf(ah)) : 0.f) - fast_sig(x3);
      s1 = (d0 * d0 + d1 * d1 + d2 * d2 + d3 * d3) * t4;
      s2 = t4;
      float b4 = fast_bce(x4, t4);
      b5 = fast_bce(x0, t0) + fast_bce(x1, t1) + fast_bce(x2, t2) + fast_bce(x3, t3) + b4;
      bo = b4;
    }
    float v0 = s1, v1 = s2, v2 = b5, v3 = bo;
    for (int off = 32; off > 0; off >>= 1) {
      v0 += __shfl_down(v0, off); v1 += __shfl_down(v1, off);
      v2 += __shfl_down(v2, off); v3 += __shfl_down(v3, off);
    }
    if (lane == 0) { lds[wid][0] = v0; lds[wid][1] = v1; lds[wid][2] = v2; lds[wid][3] = v3; }
    __syncthreads();
    if (threadIdx.x == 0) {
      float r0 = 0, r1 = 0, r2 = 0, r3 = 0;
      #pragma unroll
      for (int w = 0; w < NT / 64; ++w) {
        r0 += lds[w][0]; r1 += lds[w][1]; r2 += lds[w][2]; r3 += lds[w][3];
      }
      float* dst = ws + WS_B + j * 4;
      dst[0] = r0; dst[1] = r1; dst[2] = r2; dst[3] = r3;
    }
  }
}

__global__ __launch_bounds__(256) void yolo_fin(
    const float* __restrict__ ws, float* __restrict__ out)
{
  const int tid = threadIdx.x;
  float sh = 0.f, sl = 0.f, b5 = 0.f, bo = 0.f;
  for (int i = tid; i < NA_BLK; i += 256) { sh += ws[i * 2]; sl += ws[i * 2 + 1]; }
  const float* pb = ws + WS_B;
  for (int i = tid; i < NB_BLK; i += 256) { b5 += pb[i * 4 + 2]; bo += pb[i * 4 + 3]; }
  for (int off = 32; off > 0; off >>= 1) {
    sh += __shfl_down(sh, off); sl += __shfl_down(sl, off);
    b5 += __shfl_down(b5, off); bo += __shfl_down(bo, off);
  }
  __shared__ float red[4][4];
  int lane = tid & 63, wid = tid >> 6;
  if (lane == 0) { red[wid][0] = sh; red[wid][1] = sl; red[wid][2] = b5; red[wid][3] = bo; }
  __syncthreads();
  __shared__ float coef;
  if (tid == 0) {
    float SH = 0, SL = 0, B5 = 0, BO = 0;
    #pragma unroll
    for (int w = 0; w < 4; ++w) {
      SH += red[w][0]; SL += red[w][1]; B5 += red[w][2]; BO += red[w][3];
    }
    float all = SH + LN2 * SL;          // BCE sum over all 85 channels
    float cls = all - B5;               // classes only (c >= 5)
    const float ncls = (float)BB * (float)NCELL * 80.0f;   // 10,383,360 (<2^24)
    const float nobj = (float)BB * (float)NCELL;           // 129,792
    coef = 0.5f * cls / ncls + BO / nobj;
  }
  __syncthreads();
  if (tid < BB) {
    const float* pb2 = ws + WS_B;
    float s1 = 0.f, s2 = 0.f;
    for (int j = 0; j < NB_BLK_PB; ++j) {
      int idx = (tid * NB_BLK_PB + j) * 4;
      s1 += pb2[idx + 0]; s2 += pb2[idx + 1];
    }
    out[tid] = 2.0f * s1 + coef * s2;
  }
}

extern "C" void kernel_launch(void* const* d_in, const int* in_sizes, int n_in,
                              void* d_out, int out_size, void* d_ws, size_t ws_size,
                              hipStream_t stream) {
  const float* yp   = (const float*)d_in[0];   // y_pred (16,52,52,3,85)
  const float* yt   = (const float*)d_in[1];   // y_true (16,52,52,3,85)
  const float* anch = (const float*)d_in[2];   // (3,2)
  float* out = (float*)d_out;                  // (16,)
  float* ws  = (float*)d_ws;                   // (2048*2 + 512*4)*4 = 24 KB

  yolo_pass<<<NBLK, NT, 0, stream>>>(yp, yt, anch, ws);
  yolo_fin<<<1, 256, 0, stream>>>(ws, out);
}

// Round 7
// 27.829 us; speedup vs baseline: 16.4492x; 1.0634x over previous
//
#include <hip/hip_runtime.h>
#include <math.h>

// Geometry fixed by reference setup_inputs
#define GG 52
#define AA 3
#define BB 16
#define DD 85
#define NCELL (GG*GG*AA)           // 8112 cells per batch
#define EBAT (NCELL*DD)            // 689520 floats per batch
#define TOTV ((BB*EBAT)/4)         // 2,758,080 float4s, flat over all batches
#define NA_BLK 2048                // pass-A blocks (uniform BCE stream)
#define NB_BLK_PB 32               // pass-B blocks per batch
#define NB_BLK (NB_BLK_PB*BB)      // 512
#define NBLK (NA_BLK+NB_BLK)       // 2560 blocks in main dispatch
#define NT 256
#define STRIDE (NA_BLK*NT)         // 524288 pass-A threads
#define LN2 0.69314718055994530942f

// ws layout (floats): [0 .. NA_BLK*2)          pass-A partials {sumH, sumLog2}
//                     [WS_B .. WS_B+NB_BLK*4)  pass-B partials {s1, s2, bce5, bceObj}
#define WS_B (NA_BLK*2)

__device__ __forceinline__ float fast_sig(float x) {
  float u = __expf(-fabsf(x));
  float r = __builtin_amdgcn_rcpf(1.0f + u);
  return x >= 0.0f ? r : u * r;
}
// bce(sigmoid(x), t) = max(x,0) - x*t + ln(1+exp(-|x|))
__device__ __forceinline__ float fast_bce(float x, float t) {
  float u = __expf(-fabsf(x));
  return fmaxf(x, 0.0f) - x * t + LN2 * __log2f(1.0f + u);
}
// BCE pieces for 4 (x,t): aA += -x*t, aB += max(x,0), pr0/pr1 *= (1+exp(-|x|))
__device__ __forceinline__ void elem4(float4 p, float4 t,
                                      float& aA, float& aB, float& pr0, float& pr1) {
  #pragma unroll
  for (int k = 0; k < 4; ++k) {
    float x = (&p.x)[k], tt = (&t.x)[k];
    float u = __expf(-fabsf(x));
    aA = fmaf(-x, tt, aA);
    aB += fmaxf(x, 0.0f);
    if (k & 1) pr1 = fmaf(pr1, u, pr1);   // pr *= (1+u), two indep chains
    else       pr0 = fmaf(pr0, u, pr0);
  }
}

__global__ __launch_bounds__(NT) void yolo_pass(
    const float* __restrict__ yp, const float* __restrict__ yt,
    const float* __restrict__ anch, float* __restrict__ ws)
{
  const int bx = blockIdx.x;
  const int lane = threadIdx.x & 63, wid = threadIdx.x >> 6;
  __shared__ float lds[NT / 64][4];

  if (bx >= NB_BLK) {
    // ---------- pass A: uniform BCE over all 85 channels, fully coalesced -----
    const float4* __restrict__ vp = (const float4*)yp;
    const float4* __restrict__ vt = (const float4*)yt;
    float aA = 0.f, aB = 0.f, sl = 0.f;
    int v = (bx - NB_BLK) * NT + threadIdx.x;
    // 3-deep grid-stride; coverage of [0,TOTV) hand-verified (TOTV = 5S+136640)
    while (v + 2 * STRIDE < TOTV) {
      float4 p0 = vp[v],              t0 = vt[v];
      float4 p1 = vp[v + STRIDE],     t1 = vt[v + STRIDE];
      float4 p2 = vp[v + 2 * STRIDE], t2 = vt[v + 2 * STRIDE];
      float pr0 = 1.f, pr1 = 1.f;
      elem4(p0, t0, aA, aB, pr0, pr1);
      elem4(p1, t1, aA, aB, pr0, pr1);
      elem4(p2, t2, aA, aB, pr0, pr1);
      sl += __log2f(pr0 * pr1);           // 1 log2 per 12 elems, prod <= 2^12
      v += 3 * STRIDE;
    }
    while (v < TOTV) {
      float4 p0 = vp[v], t0 = vt[v];
      float pr0 = 1.f, pr1 = 1.f;
      elem4(p0, t0, aA, aB, pr0, pr1);
      sl += __log2f(pr0 * pr1);
      v += STRIDE;
    }
    float sh = aA + aB;
    for (int off = 32; off > 0; off >>= 1) {
      sh += __shfl_down(sh, off); sl += __shfl_down(sl, off);
    }
    if (lane == 0) { lds[wid][0] = sh; lds[wid][1] = sl; }
    __syncthreads();
    if (threadIdx.x == 0) {
      float r0 = 0, r1 = 0;
      #pragma unroll
      for (int w = 0; w < NT / 64; ++w) { r0 += lds[w][0]; r1 += lds[w][1]; }
      ws[(bx - NB_BLK) * 2 + 0] = r0;
      ws[(bx - NB_BLK) * 2 + 1] = r1;
    }
  } else {
    // ---------- pass B: one thread per cell, channels 0..4 only ---------------
    // scheduled FIRST so these latency-bound gathers overlap pass A's stream
    const int j = bx;                     // 0..511
    const int b = j >> 5;                 // batch
    const int cell = (j & 31) * NT + threadIdx.x;
    float s1 = 0.f, s2 = 0.f, b5 = 0.f, bo = 0.f;
    if (cell < NCELL) {
      const float* pp = yp + ((size_t)b * NCELL + cell) * DD;
      const float* tt = yt + ((size_t)b * NCELL + cell) * DD;
      float x0 = pp[0], x1 = pp[1], x2 = pp[2], x3 = pp[3], x4 = pp[4];
      float t0 = tt[0], t1 = tt[1], t2 = tt[2], t3 = tt[3], t4 = tt[4];
      int gi = cell / (GG * AA);          // meshgrid 'ij' dim-1
      int gj = (cell / AA) % GG;          // dim-2
      int a  = cell % AA;
      float aw = anch[a * 2 + 0], ah = anch[a * 2 + 1];
      float d0 = (t0 * (float)GG - (float)gi) - fast_sig(x0);
      float d1 = (t1 * (float)GG - (float)gj) - fast_sig(x1);
      float d2 = ((t2 > 0.f) ? (__logf(t2) - __logf(aw)) : 0.f) - fast_sig(x2);
      float d3 = ((t3 > 0.f) ? (__logf(t3) - __logf(ah)) : 0.f) - fast_sig(x3);
      s1 = (d0 * d0 + d1 * d1 + d2 * d2 + d3 * d3) * t4;
      s2 = t4;
      float b4 = fast_bce(x4, t4);
      b5 = fast_bce(x0, t0) + fast_bce(x1, t1) + fast_bce(x2, t2) + fast_bce(x3, t3) + b4;
      bo = b4;
    }
    float v0 = s1, v1 = s2, v2 = b5, v3 = bo;
    for (int off = 32; off > 0; off >>= 1) {
      v0 += __shfl_down(v0, off); v1 += __shfl_down(v1, off);
      v2 += __shfl_down(v2, off); v3 += __shfl_down(v3, off);
    }
    if (lane == 0) { lds[wid][0] = v0; lds[wid][1] = v1; lds[wid][2] = v2; lds[wid][3] = v3; }
    __syncthreads();
    if (threadIdx.x == 0) {
      float r0 = 0, r1 = 0, r2 = 0, r3 = 0;
      #pragma unroll
      for (int w = 0; w < NT / 64; ++w) {
        r0 += lds[w][0]; r1 += lds[w][1]; r2 += lds[w][2]; r3 += lds[w][3];
      }
      float* dst = ws + WS_B + j * 4;
      dst[0] = r0; dst[1] = r1; dst[2] = r2; dst[3] = r3;
    }
  }
}

#define NTF 1024
__global__ __launch_bounds__(NTF) void yolo_fin(
    const float* __restrict__ ws, float* __restrict__ out)
{
  const int tid = threadIdx.x;
  float sh = 0.f, sl = 0.f, b5 = 0.f, bo = 0.f;
  for (int i = tid; i < NA_BLK; i += NTF) { sh += ws[i * 2]; sl += ws[i * 2 + 1]; }
  const float* pb = ws + WS_B;
  for (int i = tid; i < NB_BLK; i += NTF) { b5 += pb[i * 4 + 2]; bo += pb[i * 4 + 3]; }
  for (int off = 32; off > 0; off >>= 1) {
    sh += __shfl_down(sh, off); sl += __shfl_down(sl, off);
    b5 += __shfl_down(b5, off); bo += __shfl_down(bo, off);
  }
  __shared__ float red[NTF / 64][4];
  int lane = tid & 63, wid = tid >> 6;
  if (lane == 0) { red[wid][0] = sh; red[wid][1] = sl; red[wid][2] = b5; red[wid][3] = bo; }
  __syncthreads();
  __shared__ float coef;
  if (tid == 0) {
    float SH = 0, SL = 0, B5 = 0, BO = 0;
    #pragma unroll
    for (int w = 0; w < NTF / 64; ++w) {
      SH += red[w][0]; SL += red[w][1]; B5 += red[w][2]; BO += red[w][3];
    }
    float all = SH + LN2 * SL;          // BCE sum over all 85 channels
    float cls = all - B5;               // classes only (c >= 5)
    const float ncls = (float)BB * (float)NCELL * 80.0f;   // 10,383,360 (<2^24)
    const float nobj = (float)BB * (float)NCELL;           // 129,792
    coef = 0.5f * cls / ncls + BO / nobj;
  }
  __syncthreads();
  if (tid < BB) {
    const float* pb2 = ws + WS_B;
    float s1 = 0.f, s2 = 0.f;
    for (int j = 0; j < NB_BLK_PB; ++j) {
      int idx = (tid * NB_BLK_PB + j) * 4;
      s1 += pb2[idx + 0]; s2 += pb2[idx + 1];
    }
    out[tid] = 2.0f * s1 + coef * s2;
  }
}

extern "C" void kernel_launch(void* const* d_in, const int* in_sizes, int n_in,
                              void* d_out, int out_size, void* d_ws, size_t ws_size,
                              hipStream_t stream) {
  const float* yp   = (const float*)d_in[0];   // y_pred (16,52,52,3,85)
  const float* yt   = (const float*)d_in[1];   // y_true (16,52,52,3,85)
  const float* anch = (const float*)d_in[2];   // (3,2)
  float* out = (float*)d_out;                  // (16,)
  float* ws  = (float*)d_ws;                   // (2048*2 + 512*4)*4 = 24 KB

  yolo_pass<<<NBLK, NT, 0, stream>>>(yp, yt, anch, ws);
  yolo_fin<<<1, NTF, 0, stream>>>(ws, out);
}